// Round 6
// baseline (174.507 us; speedup 1.0000x reference)
//
#include <hip/hip_runtime.h>
#include <hip/hip_bf16.h>

// LIF: V = V + (I - V)/tau; spike = V >= 1.0; V = spike ? 0 : V
// d_out = [spike_trace (0/1 f32) | voltage_trace (f32)], each T*B*N.
//
// Memory-bound streaming: 268 MB read + 537 MB write, zero reuse.
// R5 = R1 (the best structure: scalar dword, simple batch, compiler-scheduled)
// with U bumped 8 -> 16:
// - 16 independent loads in flight/wave = 4KB/wave, 32KB/CU (Little's law
//   needs ~9KB/CU at 6.3 TB/s, 900cy latency) -> 3.5x margin.
// - Halves the number of batch boundaries where the next load-batch's
//   consume-wait sits behind the previous stores in vmcnt order.
// - R3 (float4, waves/4) and R4 (explicit SW pipeline) both regressed:
//   keep max TLP (2048 waves) and let the compiler schedule.

#define LIF_T 512
#define V_TH 1.0f
#define TAU 20.0f
#define U 16

__global__ __launch_bounds__(256) void lif_kernel(const float* __restrict__ in,
                                                  float* __restrict__ spikes,
                                                  float* __restrict__ volts,
                                                  int BN) {
    const int i = blockIdx.x * blockDim.x + threadIdx.x;
    if (i >= BN) return;

    float V = 0.0f;
    size_t off = (size_t)i;
    const size_t stride = (size_t)BN;

    for (int t = 0; t < LIF_T; t += U) {
        // Batch-issue U independent loads (addresses independent of V).
        float Iv[U];
        #pragma unroll
        for (int u = 0; u < U; ++u)
            Iv[u] = __builtin_nontemporal_load(&in[off + (size_t)u * stride]);

        // Loop-carried V chain + streaming stores.
        #pragma unroll
        for (int u = 0; u < U; ++u) {
            const size_t o = off + (size_t)u * stride;
            // EXACT reference op order in f32: sub, IEEE div by 20.0f, add.
            V = V + (Iv[u] - V) / TAU;
            const bool s = (V >= V_TH);
            __builtin_nontemporal_store(s ? 1.0f : 0.0f, &spikes[o]);
            V = s ? 0.0f : V;
            __builtin_nontemporal_store(V, &volts[o]);
        }
        off += (size_t)U * stride;
    }
}

extern "C" void kernel_launch(void* const* d_in, const int* in_sizes, int n_in,
                              void* d_out, int out_size, void* d_ws, size_t ws_size,
                              hipStream_t stream) {
    const float* in = (const float*)d_in[0];
    float* out = (float*)d_out;

    const int total = in_sizes[0];          // T*B*N
    const int BN = total / LIF_T;           // 131072

    float* spikes = out;                     // first T*B*N floats
    float* volts  = out + (size_t)total;     // second T*B*N floats

    const int block = 256;
    const int grid = (BN + block - 1) / block;   // 512 blocks
    lif_kernel<<<grid, block, 0, stream>>>(in, spikes, volts, BN);
}

// Round 7
// 125.299 us; speedup vs baseline: 1.3927x; 1.3927x over previous
//
#include <hip/hip_runtime.h>
#include <hip/hip_bf16.h>

// LIF: V = V + (I - V)/tau; spike = V >= 1.0; V = spike ? 0 : V
// d_out = [spike_trace (0/1 f32) | voltage_trace (f32)], each T*B*N.
//
// Memory-bound streaming: 268 MB read + 537 MB write.
// R6 = R1 (best: scalar dword, U=8 batch, compiler-scheduled) with ONE change:
// loads are plain cached loads (no nontemporal hint). Input = 268 MB ~= the
// 256 MB Infinity Cache; across timed graph replays a cacheable read stream
// can stay L3-resident (writes remain nt so they don't compete), cutting HBM
// FETCH. nt loads forced every byte from HBM every replay.
// A/B vs R1: only the load hint differs.

#define LIF_T 512
#define V_TH 1.0f
#define TAU 20.0f
#define U 8

__global__ __launch_bounds__(256) void lif_kernel(const float* __restrict__ in,
                                                  float* __restrict__ spikes,
                                                  float* __restrict__ volts,
                                                  int BN) {
    const int i = blockIdx.x * blockDim.x + threadIdx.x;
    if (i >= BN) return;

    float V = 0.0f;
    size_t off = (size_t)i;
    const size_t stride = (size_t)BN;

    for (int t = 0; t < LIF_T; t += U) {
        // Batch-issue U independent CACHED loads (L3 can retain the stream).
        float Iv[U];
        #pragma unroll
        for (int u = 0; u < U; ++u)
            Iv[u] = in[off + (size_t)u * stride];

        // Loop-carried V chain + streaming (nt) stores.
        #pragma unroll
        for (int u = 0; u < U; ++u) {
            const size_t o = off + (size_t)u * stride;
            // EXACT reference op order in f32: sub, IEEE div by 20.0f, add.
            V = V + (Iv[u] - V) / TAU;
            const bool s = (V >= V_TH);
            __builtin_nontemporal_store(s ? 1.0f : 0.0f, &spikes[o]);
            V = s ? 0.0f : V;
            __builtin_nontemporal_store(V, &volts[o]);
        }
        off += (size_t)U * stride;
    }
}

extern "C" void kernel_launch(void* const* d_in, const int* in_sizes, int n_in,
                              void* d_out, int out_size, void* d_ws, size_t ws_size,
                              hipStream_t stream) {
    const float* in = (const float*)d_in[0];
    float* out = (float*)d_out;

    const int total = in_sizes[0];          // T*B*N
    const int BN = total / LIF_T;           // 131072

    float* spikes = out;                     // first T*B*N floats
    float* volts  = out + (size_t)total;     // second T*B*N floats

    const int block = 256;
    const int grid = (BN + block - 1) / block;   // 512 blocks
    lif_kernel<<<grid, block, 0, stream>>>(in, spikes, volts, BN);
}